// Round 1
// baseline (590.946 us; speedup 1.0000x reference)
//
#include <hip/hip_runtime.h>

#define NJ 14
#define COLN 14

// acc[0] = d1 + d2 (double), acc[1] = sum(v) (double)
__global__ __launch_bounds__(256) void mse2_reduce(
    const float* __restrict__ o, const float* __restrict__ h,
    const float* __restrict__ t, const float* __restrict__ v,
    double* __restrict__ acc, int no4, int nh4, int nv4)
{
    const int tid    = blockIdx.x * blockDim.x + threadIdx.x;
    const int stride = gridDim.x * blockDim.x;

    float sumD = 0.f;   // partial of d1 + d2
    float sumV = 0.f;   // partial of sum(v)

    // ---- segment 1: o  [B, 2*NJ, 14, 14], pp target ----
    for (int i = tid; i < no4; i += stride) {
        float4 ov = ((const float4*)o)[i];
        int e0    = i * 4;                 // flat element index
        int plane = e0 / 196;              // b*28 + ch
        int p     = e0 - plane * 196;      // 0..192 (multiple of 4)
        int b     = plane / 28;
        int ch    = plane - b * 28;
        bool isx  = ch < NJ;
        int  j    = isx ? ch : (ch - NJ);
        float tp  = t[(b * NJ + j) * 2 + (isx ? 0 : 1)] * 224.0f;
        #pragma unroll
        for (int e = 0; e < 4; ++e) {
            int pe = p + e;
            int a  = pe / 14;
            int c  = pe - a * 14;
            float pp = tp - (float)((isx ? c : a) * 14);
            float d  = (&ov.x)[e] - pp;
            sumD += d * d;
        }
    }

    // ---- segment 2: h  [B, NJ, 14, 14], one-hot target ----
    for (int i = tid; i < nh4; i += stride) {
        float4 hv = ((const float4*)h)[i];
        int e0    = i * 4;
        int plane = e0 / 196;              // b*NJ + j
        int p     = e0 - plane * 196;
        float tx  = t[plane * 2 + 0] * 14.0f;
        float ty  = t[plane * 2 + 1] * 14.0f;
        float vis = v[plane];              // {0,1}
        int xi = (int)tx; xi = xi < 0 ? 0 : (xi > 13 ? 13 : xi);
        int yi = (int)ty; yi = yi < 0 ? 0 : (yi > 13 ? 13 : yi);
        #pragma unroll
        for (int e = 0; e < 4; ++e) {
            int pe = p + e;
            int a  = pe / 14;
            int c  = pe - a * 14;
            float ttv = (a == xi && c == yi) ? vis : 0.0f;
            float d   = (&hv.x)[e] - ttv;
            sumD += d * d;
        }
    }

    // ---- segment 3: sum(v) ----
    for (int i = tid; i < nv4; i += stride) {
        float4 vv = ((const float4*)v)[i];
        sumV += (vv.x + vv.y) + (vv.z + vv.w);
    }

    // ---- reduction: wave shfl (64 lanes) -> LDS -> block -> atomic ----
    double dD = (double)sumD, dV = (double)sumV;
    #pragma unroll
    for (int off = 32; off > 0; off >>= 1) {
        dD += __shfl_down(dD, off);
        dV += __shfl_down(dV, off);
    }
    __shared__ double sD[4], sV[4];
    int wid = threadIdx.x >> 6, lane = threadIdx.x & 63;
    if (lane == 0) { sD[wid] = dD; sV[wid] = dV; }
    __syncthreads();
    if (threadIdx.x == 0) {
        double tD = sD[0] + sD[1] + sD[2] + sD[3];
        double tV = sV[0] + sV[1] + sV[2] + sV[3];
        atomicAdd(&acc[0], tD);
        atomicAdd(&acc[1], tV);
    }
}

__global__ void mse2_finalize(const double* __restrict__ acc, float* __restrict__ out)
{
    out[0] = (float)(acc[0] / (acc[1] * 0.5));
}

extern "C" void kernel_launch(void* const* d_in, const int* in_sizes, int n_in,
                              void* d_out, int out_size, void* d_ws, size_t ws_size,
                              hipStream_t stream)
{
    const float* o = (const float*)d_in[0];
    const float* h = (const float*)d_in[1];
    const float* t = (const float*)d_in[2];
    const float* v = (const float*)d_in[3];

    int no = in_sizes[0];   // B * 2*NJ * 196
    int nh = in_sizes[1];   // B * NJ * 196
    int nv = in_sizes[3];   // B * NJ

    double* acc = (double*)d_ws;
    hipMemsetAsync(acc, 0, 2 * sizeof(double), stream);

    int grid = 2048;
    mse2_reduce<<<grid, 256, 0, stream>>>(o, h, t, v, acc,
                                          no / 4, nh / 4, nv / 4);
    mse2_finalize<<<1, 1, 0, stream>>>(acc, (float*)d_out);
}